// Round 4
// baseline (168.721 us; speedup 1.0000x reference)
//
#include <hip/hip_runtime.h>

typedef __attribute__((ext_vector_type(8))) short bf16x8;
typedef __attribute__((ext_vector_type(4))) float f32x4;
typedef unsigned int u32;
typedef unsigned short u16;
typedef unsigned long long u64;

#define S0 384
#define PLANE0 (384 * 384)

__device__ __forceinline__ u16 bfr(float f) {   // f32 -> bf16 RNE
    u32 b = __float_as_uint(f);
    b += 0x7fff + ((b >> 16) & 1);
    return (u16)(b >> 16);
}

// ---------------------------------------------------------------------------
// Stage 1: v[k,m,d] = lin0_b[m] + sum_{r<128} lin0_w[m,r] * feats[3r+k, d]
// ---------------------------------------------------------------------------
__global__ void k_v(const float* __restrict__ V,
                    const float* __restrict__ lin0_w,
                    const float* __restrict__ lin0_b,
                    float* __restrict__ v_out) {
    int blk = blockIdx.x;          // 0..194
    int k = blk / 65, m = blk % 65;
    int d = threadIdx.x;           // 0..255
    int t = d >> 5, f = d & 31;
    const float* vbase = V + (size_t)t * 384 * 33 + f;
    float acc = lin0_b[m];
    for (int r = 0; r < 128; ++r) {
        float w = lin0_w[m * 130 + r];
        acc += w * vbase[(3 * r + k) * 33];
    }
    v_out[(size_t)blk * 256 + d] = acc;
}

// ---------------------------------------------------------------------------
// Stage 2: attention scalars A[k,t] (9 floats)
// ---------------------------------------------------------------------------
__global__ void k_att(const float* __restrict__ v,
                      const float* __restrict__ att_w,
                      const float* __restrict__ att_b,
                      const float* __restrict__ agg,
                      float* __restrict__ A_out) {
    int k = blockIdx.x;
    int tid = threadIdx.x;
    __shared__ float wv1[256], wv2[256];
    __shared__ float sbuf[3][65];
    __shared__ float Ck_s;
    __shared__ float sm[3];
    {
        int d = tid;
        float a1 = 0.f, a2 = 0.f;
        for (int h = 0; h < 64; ++h) {
            float w = att_w[((size_t)(k * 64 + h)) * 256 + d];
            a1 += agg[k * 128 + h] * w;
            a2 += agg[k * 128 + 64 + h] * w;
        }
        wv1[d] = a1;
        wv2[d] = a2;
    }
    if (tid == 0) {
        float c = 0.f;
        for (int h = 0; h < 64; ++h)
            c += (agg[k * 128 + h] + agg[k * 128 + 64 + h]) * att_b[k * 64 + h];
        Ck_s = c;
    }
    __syncthreads();
    if (tid < 195) {
        int t = tid / 65, m = tid % 65;
        const float* vt = v + ((size_t)(t * 65 + m)) * 256;
        const float* vk = v + ((size_t)(k * 65 + m)) * 256;
        float s = Ck_s;
        for (int d = 0; d < 256; ++d)
            s += vt[d] * wv1[d] + vk[d] * wv2[d];
        s = s > 0.f ? s : 0.01f * s;
        sbuf[t][m] = s;
    }
    __syncthreads();
    if (tid < 3) {
        float mx = sbuf[tid][0];
        for (int m = 1; m < 65; ++m) mx = fmaxf(mx, sbuf[tid][m]);
        sm[tid] = mx;
    }
    __syncthreads();
    if (tid == 0) {
        float mx = fmaxf(sm[0], fmaxf(sm[1], sm[2]));
        float e0 = __expf(sm[0] - mx), e1 = __expf(sm[1] - mx), e2 = __expf(sm[2] - mx);
        float inv = 1.f / (e0 + e1 + e2);
        A_out[k * 3 + 0] = e0 * inv;
        A_out[k * 3 + 1] = e1 * inv;
        A_out[k * 3 + 2] = e2 * inv;
    }
}

// ---------------------------------------------------------------------------
// Composed-conv weight prep: E[o, tap, i] (bf16), tap=(dy*3+dx), and
// b_eff[o] = cb[o] + sum_m cb[m]*sum(W[o][m][:][:]).
// grid 128 blocks (o) x 128 threads (i).
// ---------------------------------------------------------------------------
__global__ void k_prep_E(const float* __restrict__ cw, const float* __restrict__ cb,
                         u16* __restrict__ Ebf, float* __restrict__ beff) {
    int o = blockIdx.x, i = threadIdx.x;
    __shared__ float4 Wo[128];
    __shared__ float red[128];
    Wo[i] = *(const float4*)(cw + (size_t)(o * 128 + i) * 4);
    __syncthreads();
    float a9[9];
#pragma unroll
    for (int q = 0; q < 9; ++q) a9[q] = 0.f;
    for (int m = 0; m < 128; ++m) {
        float4 w1 = *(const float4*)(cw + (size_t)(m * 128 + i) * 4);  // W[m][i]
        float4 w2 = Wo[m];                                             // W[o][m]
        a9[0] += w2.x * w1.x;
        a9[1] += w2.x * w1.y + w2.y * w1.x;
        a9[2] += w2.y * w1.y;
        a9[3] += w2.x * w1.z + w2.z * w1.x;
        a9[4] += w2.x * w1.w + w2.y * w1.z + w2.z * w1.y + w2.w * w1.x;
        a9[5] += w2.y * w1.w + w2.w * w1.y;
        a9[6] += w2.z * w1.z;
        a9[7] += w2.z * w1.w + w2.w * w1.z;
        a9[8] += w2.w * w1.w;
    }
#pragma unroll
    for (int q = 0; q < 9; ++q)
        Ebf[(size_t)o * 1152 + q * 128 + i] = bfr(a9[q]);
    float4 wo = Wo[i];
    red[i] = cb[i] * (wo.x + wo.y + wo.z + wo.w);
    __syncthreads();
    for (int s = 64; s > 0; s >>= 1) {
        if (i < s) red[i] += red[i + s];
        __syncthreads();
    }
    if (i == 0) beff[o] = cb[o] + red[0];
}

// ---------------------------------------------------------------------------
// Fused 3x3 conv (composed 2x2∘2x2) on pad2(graph*att9), 128oc x 64px x 2rows
// per block, K = 9taps*128ic = 1152, split in 2 ic-half phases.
// LDS: [row 0..3][px 0..65][ic-half 64] bf16, 16B-group XOR swizzle
//   byte = ((r*66+p)<<7) + ((h ^ (p&7))<<4),  h = ic-octet 0..7.
// Epilogue: out = relu(pl*(acc + beff) + graph).
// grid (6, 192), 256 threads.
// ---------------------------------------------------------------------------
__global__ __launch_bounds__(256) void k_conv9(
        const float* __restrict__ graph,
        const short* __restrict__ Ebf,
        const float* __restrict__ A9g,
        const float* __restrict__ beff,
        const float* __restrict__ pl,
        float* __restrict__ out) {
    __shared__ __align__(16) char BtB[4 * 66 * 128];   // 33792 B
    const int tid = threadIdx.x;
    const int lane = tid & 63, wave = tid >> 6;
    const int l15 = lane & 15, l16 = lane >> 4;
    const int sp = tid & 15;            // staging px lane
    const int hh = (tid >> 4) & 7;      // staging ic-octet
    const int rr = tid >> 7;            // staging row-pair (0..1)
    const int y0 = blockIdx.y * 2, x0 = blockIdx.x * 64;
    const int ocbase = wave * 32;

    // per-thread staging factors / clamped cols
    float fct[4][5];
    int cx[5], rowoff[4];
    {
        int xm[5]; bool cv[5];
#pragma unroll
        for (int j = 0; j < 5; ++j) {
            int x = x0 + sp + 16 * j;
            cv[j] = x < S0;
            cx[j] = cv[j] ? x : S0 - 1;
            xm[j] = x % 3;
        }
#pragma unroll
        for (int r = 0; r < 4; ++r) {
            int y = y0 + r;
            bool rv = y < S0;
            rowoff[r] = (rv ? y : S0 - 1) * S0;
            float a0 = rv ? A9g[(y % 3) * 3 + 0] : 0.f;
            float a1 = rv ? A9g[(y % 3) * 3 + 1] : 0.f;
            float a2 = rv ? A9g[(y % 3) * 3 + 2] : 0.f;
#pragma unroll
            for (int j = 0; j < 5; ++j) {
                float a = (xm[j] == 0) ? a0 : ((xm[j] == 1) ? a1 : a2);
                fct[r][j] = cv[j] ? a : 0.f;
            }
        }
    }

    f32x4 acc[2][2][4];
#pragma unroll
    for (int t2 = 0; t2 < 2; ++t2)
#pragma unroll
        for (int a = 0; a < 2; ++a)
#pragma unroll
            for (int b = 0; b < 4; ++b)
                acc[t2][a][b] = (f32x4){0.f, 0.f, 0.f, 0.f};

#pragma unroll
    for (int ph = 0; ph < 2; ++ph) {
        if (ph) __syncthreads();   // phase-0 readers done before overwrite

        // ---- stage 64 ic x 4 rows x 66 px ----
        const float* gb = graph + (size_t)(ph * 64 + hh * 8) * PLANE0;
#pragma unroll
        for (int rl = 0; rl < 2; ++rl) {
            int r = rr * 2 + rl;
            const float* gr = gb + rowoff[r];
#pragma unroll
            for (int j = 0; j < 5; ++j) {
                if (j < 4 || sp < 2) {
                    int p = sp + 16 * j;
                    float f = fct[r][j];
                    const float* g0 = gr + cx[j];
                    u16 q[8];
#pragma unroll
                    for (int e = 0; e < 8; ++e)
                        q[e] = bfr(g0[(size_t)e * PLANE0] * f);
                    uint4 w;
                    w.x = (u32)q[0] | ((u32)q[1] << 16);
                    w.y = (u32)q[2] | ((u32)q[3] << 16);
                    w.z = (u32)q[4] | ((u32)q[5] << 16);
                    w.w = (u32)q[6] | ((u32)q[7] << 16);
                    *(uint4*)(BtB + ((r * 66 + p) << 7) + ((hh ^ (p & 7)) << 4)) = w;
                }
            }
        }
        __syncthreads();

        // ---- MFMA: 9 taps x 2 ic-groups = 18 k-steps, 288 MFMA/wave ----
#pragma unroll
        for (int tap = 0; tap < 9; ++tap) {
            const int dy = tap / 3, dx = tap % 3;
            const int pm = l15 + dx;
#pragma unroll
            for (int icg = 0; icg < 2; ++icg) {
                const short* Ap = Ebf + (size_t)(ocbase + l15) * 1152
                                  + tap * 128 + ph * 64 + icg * 32 + l16 * 8;
                bf16x8 a0 = *(const bf16x8*)Ap;
                bf16x8 a1 = *(const bf16x8*)(Ap + 16 * 1152);
                const int hs = ((icg * 4 + l16) ^ (pm & 7)) << 4;
#pragma unroll
                for (int t2 = 0; t2 < 2; ++t2) {
#pragma unroll
                    for (int ni = 0; ni < 4; ++ni) {
                        bf16x8 bv = *(const bf16x8*)(BtB
                            + (((t2 + dy) * 66 + ni * 16 + pm) << 7) + hs);
                        acc[t2][0][ni] = __builtin_amdgcn_mfma_f32_16x16x32_bf16(a0, bv, acc[t2][0][ni], 0, 0, 0);
                        acc[t2][1][ni] = __builtin_amdgcn_mfma_f32_16x16x32_bf16(a1, bv, acc[t2][1][ni], 0, 0, 0);
                    }
                }
            }
        }
    }

    // ---- epilogue: out = relu(pl*(acc + beff) + graph) ----
    float plv = pl[0];
#pragma unroll
    for (int t2 = 0; t2 < 2; ++t2) {
        int yy = y0 + t2;
#pragma unroll
        for (int mi = 0; mi < 2; ++mi) {
#pragma unroll
            for (int r4 = 0; r4 < 4; ++r4) {
                int oc = ocbase + mi * 16 + l16 * 4 + r4;
                float bias = beff[oc];
                const float* grow = graph + (size_t)oc * PLANE0 + (size_t)yy * S0 + x0;
                float* orow = out + (size_t)oc * PLANE0 + (size_t)yy * S0 + x0;
#pragma unroll
                for (int ni = 0; ni < 4; ++ni) {
                    int xx = ni * 16 + l15;
                    float v = plv * (acc[t2][mi][ni][r4] + bias) + grow[xx];
                    orow[xx] = v > 0.f ? v : 0.f;
                }
            }
        }
    }
}

// ---------------------------------------------------------------------------
extern "C" void kernel_launch(void* const* d_in, const int* in_sizes, int n_in,
                              void* d_out, int out_size, void* d_ws, size_t ws_size,
                              hipStream_t stream) {
    (void)in_sizes; (void)n_in; (void)out_size; (void)ws_size;
    const float* V      = (const float*)d_in[0];
    const float* graph  = (const float*)d_in[1];
    const float* lin0_w = (const float*)d_in[4];
    const float* lin0_b = (const float*)d_in[5];
    const float* att_w  = (const float*)d_in[6];
    const float* att_b  = (const float*)d_in[7];
    const float* agg    = (const float*)d_in[8];
    const float* pl     = (const float*)d_in[9];
    const float* cw     = (const float*)d_in[10];
    const float* cb     = (const float*)d_in[11];
    float* out = (float*)d_out;

    char* ws = (char*)d_ws;
    float* v_ws = (float*)ws;                       // 3*65*256 f32 (199680 B)
    float* A_ws = (float*)(ws + 200704);            // 9 f32
    u16*   Ebf  = (u16*)(ws + 200768);              // 128*1152 bf16 = 294912 B
    float* beff = (float*)(ws + 495680);            // 128 f32

    k_prep_E<<<128, 128, 0, stream>>>(cw, cb, Ebf, beff);
    k_v<<<195, 256, 0, stream>>>(V, lin0_w, lin0_b, v_ws);
    k_att<<<3, 256, 0, stream>>>(v_ws, att_w, att_b, agg, A_ws);
    k_conv9<<<dim3(6, 192), 256, 0, stream>>>(
        graph, (const short*)Ebf, A_ws, beff, pl, out);
}